// Round 1
// baseline (258.740 us; speedup 1.0000x reference)
//
#include <hip/hip_runtime.h>
#include <hip/hip_bf16.h>

#define N_NODES 50000
#define N_EDGES 800000
#define D_IN    1024
#define D_OUT   256
#define CAP     64
#define LEAKY   0.01f

typedef __attribute__((ext_vector_type(8))) short bf16x8;
typedef __attribute__((ext_vector_type(4))) float f32x4;
typedef unsigned short u16;

__device__ __forceinline__ u16 f2bfu(float f) {
  uint32_t x = __float_as_uint(f);
  uint32_t r = (x + 0x7FFFu + ((x >> 16) & 1u)) >> 16;  // RNE
  return (u16)r;
}
__device__ __forceinline__ float bfu2f(u16 u) {
  return __uint_as_float(((uint32_t)u) << 16);
}

// ---------------------------------------------------------------------------
// Kernel 1: weight fp32 [K=1024][N=256] -> transposed bf16 WT [N=256][K=1024]
// 32768 threads; reads are uncoalesced 4B but W is 1 MB (L2-resident), writes
// are coalesced b128.
// ---------------------------------------------------------------------------
__global__ __launch_bounds__(256) void wconv_kernel(const float* __restrict__ w,
                                                    u16* __restrict__ wt) {
  const int t  = blockIdx.x * 256 + threadIdx.x;   // 0..32767
  const int kc = (t & 127) * 8;                    // k chunk of 8
  const int n  = t >> 7;                           // 0..255
  bf16x8 v;
#pragma unroll
  for (int i = 0; i < 8; ++i) v[i] = (short)f2bfu(w[(size_t)(kc + i) * D_OUT + n]);
  *(bf16x8*)&wt[(size_t)n * D_IN + kc] = v;
}

// ---------------------------------------------------------------------------
// Kernel 2: GEMM support[m][n] = x[m][:] . W[:][n], bf16 MFMA, out bf16.
// Tile: BM=128, BN=256 (full), BK=32. 512 threads = 8 waves (2 m-groups x
// 4 n-groups), each wave 64x64 via acc[4][4] of 16x16x32 fragments.
// Swapped operands: A-op = W^T tile (n x k), B-op = x tile (k, m-col) so that
// D[n][m] lane layout gives 4 consecutive n per lane -> packed 8B stores.
// ---------------------------------------------------------------------------
#define GBM 128
#define GBK 32
#define GPAD 40   // 80-byte LDS rows: 16B-aligned, spreads b128 reads on banks

__global__ __launch_bounds__(512) void gemm_kernel(const float* __restrict__ x,
                                                   const u16* __restrict__ wt,
                                                   u16* __restrict__ support) {
  __shared__ u16 Xlds[GBM][GPAD];
  __shared__ u16 Wlds[D_OUT][GPAD];
  const int tid  = threadIdx.x;
  const int lane = tid & 63;
  const int wid  = tid >> 6;
  const int wn   = wid & 3;    // n-group (64 cols)
  const int wm   = wid >> 2;   // m-group (64 rows)
  const int l15  = lane & 15;
  const int l16  = lane >> 4;
  const int m0   = blockIdx.x * GBM;

  f32x4 acc[4][4];
#pragma unroll
  for (int i = 0; i < 4; ++i)
#pragma unroll
    for (int j = 0; j < 4; ++j) acc[i][j] = (f32x4)0.0f;

  // X staging: thread -> (row, 8-col chunk); coalesced float4 pairs.
  const int xrow = tid >> 2;
  const int xcol = (tid & 3) * 8;
  const int xrg  = min(m0 + xrow, N_NODES - 1);   // clamp tail reads
  const float* xp = x + (size_t)xrg * D_IN + xcol;

  // W staging: thread -> (n row, 16-k chunk) of WT; b128 loads + b128 writes.
  const int wtn = tid >> 1;
  const int wtk = (tid & 1) * 16;
  const u16* wp = wt + (size_t)wtn * D_IN + wtk;

  for (int k0 = 0; k0 < D_IN; k0 += GBK) {
    const float4 xa = *(const float4*)(xp + k0);
    const float4 xb = *(const float4*)(xp + k0 + 4);
    bf16x8 xv;
    xv[0] = (short)f2bfu(xa.x); xv[1] = (short)f2bfu(xa.y);
    xv[2] = (short)f2bfu(xa.z); xv[3] = (short)f2bfu(xa.w);
    xv[4] = (short)f2bfu(xb.x); xv[5] = (short)f2bfu(xb.y);
    xv[6] = (short)f2bfu(xb.z); xv[7] = (short)f2bfu(xb.w);
    const bf16x8 w0 = *(const bf16x8*)(wp + k0);
    const bf16x8 w1 = *(const bf16x8*)(wp + k0 + 8);

    *(bf16x8*)&Xlds[xrow][xcol]    = xv;
    *(bf16x8*)&Wlds[wtn][wtk]      = w0;
    *(bf16x8*)&Wlds[wtn][wtk + 8]  = w1;
    __syncthreads();

    bf16x8 af[4], bfr[4];
#pragma unroll
    for (int i = 0; i < 4; ++i)
      af[i] = *(const bf16x8*)&Wlds[wn * 64 + i * 16 + l15][l16 * 8];
#pragma unroll
    for (int j = 0; j < 4; ++j)
      bfr[j] = *(const bf16x8*)&Xlds[wm * 64 + j * 16 + l15][l16 * 8];
#pragma unroll
    for (int i = 0; i < 4; ++i)
#pragma unroll
      for (int j = 0; j < 4; ++j)
        acc[i][j] = __builtin_amdgcn_mfma_f32_16x16x32_bf16(af[i], bfr[j], acc[i][j], 0, 0, 0);
    __syncthreads();
  }

  // D[i'][j']: i' = n-offset = l16*4 + reg, j' = m-offset = l15.
#pragma unroll
  for (int j = 0; j < 4; ++j) {
    const int m = m0 + wm * 64 + j * 16 + l15;
    if (m < N_NODES) {
#pragma unroll
      for (int i = 0; i < 4; ++i) {
        const int n = wn * 64 + i * 16 + l16 * 4;
        ushort4 o;
        o.x = f2bfu(acc[i][j][0]);
        o.y = f2bfu(acc[i][j][1]);
        o.z = f2bfu(acc[i][j][2]);
        o.w = f2bfu(acc[i][j][3]);
        *(ushort4*)&support[(size_t)m * D_OUT + n] = o;
      }
    }
  }
}

// ---------------------------------------------------------------------------
// Kernel 3: build capped per-dst edge lists. 800K int atomics, no float
// atomics anywhere.
// ---------------------------------------------------------------------------
__global__ __launch_bounds__(256) void build_kernel(const int* __restrict__ ei,
                                                    const float* __restrict__ ew,
                                                    int* __restrict__ deg,
                                                    int* __restrict__ csr_src,
                                                    float* __restrict__ csr_w) {
  const int e = blockIdx.x * 256 + threadIdx.x;
  if (e >= N_EDGES) return;
  const int src = ei[e];
  const int dst = ei[N_EDGES + e];
  const float w = ew[e];
  const int slot = atomicAdd(&deg[dst], 1);
  if (slot < CAP) {
    csr_src[dst * CAP + slot] = src;
    csr_w [dst * CAP + slot] = w;
  }
}

// ---------------------------------------------------------------------------
// Kernel 4: per-node gather-aggregate + epilogue. One wave per node; lane
// owns 4 channels. Gathers 512B/edge coalesced from bf16 support (L3-res).
// ---------------------------------------------------------------------------
__global__ __launch_bounds__(256) void agg_kernel(const u16* __restrict__ support,
                                                  const int* __restrict__ deg,
                                                  const int* __restrict__ csr_src,
                                                  const float* __restrict__ csr_w,
                                                  const float* __restrict__ norm,
                                                  const float* __restrict__ bias,
                                                  float* __restrict__ out) {
  const int lane = threadIdx.x & 63;
  const int wid  = threadIdx.x >> 6;
  const int node = blockIdx.x * 4 + wid;   // grid = 12500 -> exactly 50000
  const int d    = min(deg[node], CAP);
  const int cb   = node * CAP;
  float a0 = 0.f, a1 = 0.f, a2 = 0.f, a3 = 0.f;
  for (int s = 0; s < d; ++s) {
    const int   src = csr_src[cb + s];   // wave-uniform -> broadcast
    const float wgt = csr_w [cb + s];
    const ushort4 v = *(const ushort4*)&support[(size_t)src * D_OUT + lane * 4];
    a0 = fmaf(wgt, bfu2f(v.x), a0);
    a1 = fmaf(wgt, bfu2f(v.y), a1);
    a2 = fmaf(wgt, bfu2f(v.z), a2);
    a3 = fmaf(wgt, bfu2f(v.w), a3);
  }
  const float rn = 1.0f / norm[node];
  const float4 b = *(const float4*)&bias[lane * 4];
  float o0 = fmaf(a0, rn, b.x);
  float o1 = fmaf(a1, rn, b.y);
  float o2 = fmaf(a2, rn, b.z);
  float o3 = fmaf(a3, rn, b.w);
  o0 = o0 > 0.f ? o0 : o0 * LEAKY;
  o1 = o1 > 0.f ? o1 : o1 * LEAKY;
  o2 = o2 > 0.f ? o2 : o2 * LEAKY;
  o3 = o3 > 0.f ? o3 : o3 * LEAKY;
  *(float4*)&out[(size_t)node * D_OUT + lane * 4] = make_float4(o0, o1, o2, o3);
}

// ---------------------------------------------------------------------------
// ws layout (bytes):
//   support  bf16  [50000][256]   @ 0          25,600,000
//   WT       bf16  [256][1024]    @ 25,600,000    524,288
//   csr_src  int   [50000][64]    @ 26,124,288 12,800,000
//   csr_w    float [50000][64]    @ 38,924,288 12,800,000
//   deg      int   [50000]        @ 51,724,288    200,000
// total 51,924,288 B
// ---------------------------------------------------------------------------
extern "C" void kernel_launch(void* const* d_in, const int* in_sizes, int n_in,
                              void* d_out, int out_size, void* d_ws, size_t ws_size,
                              hipStream_t stream) {
  const float* x    = (const float*)d_in[0];
  const float* w    = (const float*)d_in[1];
  const float* bias = (const float*)d_in[2];
  const int*   ei   = (const int*)d_in[3];
  const float* ew   = (const float*)d_in[4];
  const float* norm = (const float*)d_in[5];
  float* out = (float*)d_out;

  char* ws = (char*)d_ws;
  u16*   support = (u16*)  (ws);
  u16*   wt      = (u16*)  (ws + 25600000);
  int*   csr_src = (int*)  (ws + 26124288);
  float* csr_w   = (float*)(ws + 38924288);
  int*   deg     = (int*)  (ws + 51724288);

  hipMemsetAsync(deg, 0, N_NODES * sizeof(int), stream);
  wconv_kernel<<<128, 256, 0, stream>>>(w, wt);
  gemm_kernel<<<(N_NODES + GBM - 1) / GBM, 512, 0, stream>>>(x, wt, support);
  build_kernel<<<(N_EDGES + 255) / 256, 256, 0, stream>>>(ei, ew, deg, csr_src, csr_w);
  agg_kernel<<<N_NODES / 4, 256, 0, stream>>>(support, deg, csr_src, csr_w, norm, bias, out);
}

// Round 2
// 238.095 us; speedup vs baseline: 1.0867x; 1.0867x over previous
//
#include <hip/hip_runtime.h>
#include <hip/hip_bf16.h>

#define N_NODES 50000
#define N_EDGES 800000
#define D_IN    1024
#define D_OUT   256
#define CAP     64
#define LEAKY   0.01f

typedef __attribute__((ext_vector_type(8))) short bf16x8;
typedef __attribute__((ext_vector_type(4))) float f32x4;
typedef unsigned short u16;

__device__ __forceinline__ u16 f2bfu(float f) {
  uint32_t x = __float_as_uint(f);
  uint32_t r = (x + 0x7FFFu + ((x >> 16) & 1u)) >> 16;  // RNE
  return (u16)r;
}
__device__ __forceinline__ float bfu2f(u16 u) {
  return __uint_as_float(((uint32_t)u) << 16);
}
// XOR bank swizzle: flip byte bits 4-6 with row (byte>>7) low bits.
__device__ __forceinline__ int swz(int b) { return b ^ (((b >> 7) & 7) << 4); }

__device__ __forceinline__ void gll16(const void* g, void* l) {
  __builtin_amdgcn_global_load_lds(
      (const __attribute__((address_space(1))) uint32_t*)g,
      (__attribute__((address_space(3))) uint32_t*)l, 16, 0, 0);
}

// ---------------------------------------------------------------------------
// Kernel 1: weight fp32 [K=1024][N=256] -> bf16 "LDS image":
// 16 k-tiles, each a swizzled [256 n][64 k] block of 32768 B, so the GEMM can
// global_load_lds it linearly and ds_read with the same swizzle.
// Reads are coalesced (consecutive t -> consecutive n).
// ---------------------------------------------------------------------------
__global__ __launch_bounds__(256) void wconv_kernel(const float* __restrict__ w,
                                                    char* __restrict__ img) {
  const int t   = blockIdx.x * 256 + threadIdx.x;   // 0..32767
  const int n   = t & 255;
  const int kc  = (t >> 8) * 8;                     // k chunk of 8
  const int kt  = kc >> 6;
  const int kin = kc & 63;
  bf16x8 v;
#pragma unroll
  for (int i = 0; i < 8; ++i) v[i] = (short)f2bfu(w[(size_t)(kc + i) * D_OUT + n]);
  *(bf16x8*)(img + kt * 32768 + swz(n * 128 + kin * 2)) = v;
}

// ---------------------------------------------------------------------------
// Kernel 2: GEMM support = x @ W, bf16 MFMA.
// BM=64, BN=256(full), BK=64. 512 thr = 8 waves (2m x 4n), wave = 32m x 64n,
// acc[4][2]. Double-buffered LDS, one barrier per K-step:
//   issue W(t+1) global_load_lds + X(t+1) global loads -> MFMA on buf[t]
//   -> cvt+ds_write X(t+1) -> barrier.
// Both LDS tiles XOR-swizzled; frag reads are bank-conflict-free (8 words/bank).
// ---------------------------------------------------------------------------
#define BM 64
#define BK 64
#define KSTEPS (D_IN / BK)   // 16

__global__ __launch_bounds__(512) void gemm_kernel(const float* __restrict__ x,
                                                   const char* __restrict__ img,
                                                   u16* __restrict__ support) {
  __shared__ u16 Wbuf[2][16384];  // [256 n][64 k] swizzled, 32 KB each
  __shared__ u16 Xbuf[2][4096];   // [64 m][64 k] swizzled,  8 KB each

  const int tid  = threadIdx.x;
  const int lane = tid & 63;
  const int wid  = tid >> 6;
  const int wn   = wid & 3;    // n-group (64 cols)
  const int wm   = wid >> 2;   // m-group (32 rows)
  const int l15  = lane & 15;
  const int l16  = lane >> 4;
  const int m0   = blockIdx.x * BM;

  f32x4 acc[4][2];
#pragma unroll
  for (int i = 0; i < 4; ++i)
#pragma unroll
    for (int j = 0; j < 2; ++j) acc[i][j] = (f32x4)0.0f;

  // X staging: thread -> (row, 8-k chunk), coalesced float4 pairs.
  const int xrow = tid >> 3;           // 0..63
  const int xk8  = (tid & 7) * 8;      // 0..56
  const int xrg  = min(m0 + xrow, N_NODES - 1);
  const float* xp = x + (size_t)xrg * D_IN + xk8;
  const int xw_off = swz(xrow * 128 + xk8 * 2);

  // Fragment read byte offsets (constant across steps).
  int a_off[2][4], b_off[2][2];
#pragma unroll
  for (int ks = 0; ks < 2; ++ks) {
#pragma unroll
    for (int i = 0; i < 4; ++i)
      a_off[ks][i] = swz((wn * 64 + i * 16 + l15) * 128 + ks * 64 + l16 * 16);
#pragma unroll
    for (int j = 0; j < 2; ++j)
      b_off[ks][j] = swz((wm * 32 + j * 16 + l15) * 128 + ks * 64 + l16 * 16);
  }

  // ---- prologue: stage k-tile 0 into buffer 0 ----
#pragma unroll
  for (int r = 0; r < 4; ++r)
    gll16(img + r * 8192 + tid * 16, (char*)&Wbuf[0][0] + r * 8192 + tid * 16);
  {
    const float4 xa = *(const float4*)(xp);
    const float4 xb = *(const float4*)(xp + 4);
    bf16x8 xv;
    xv[0] = (short)f2bfu(xa.x); xv[1] = (short)f2bfu(xa.y);
    xv[2] = (short)f2bfu(xa.z); xv[3] = (short)f2bfu(xa.w);
    xv[4] = (short)f2bfu(xb.x); xv[5] = (short)f2bfu(xb.y);
    xv[6] = (short)f2bfu(xb.z); xv[7] = (short)f2bfu(xb.w);
    *(bf16x8*)((char*)&Xbuf[0][0] + xw_off) = xv;
  }
  __syncthreads();

  for (int kt = 0; kt < KSTEPS; ++kt) {
    const int cur = kt & 1;
    float4 xa, xb;
    if (kt < KSTEPS - 1) {
      // issue next W tile (async to LDS) and next X loads (to regs)
#pragma unroll
      for (int r = 0; r < 4; ++r)
        gll16(img + (size_t)(kt + 1) * 32768 + r * 8192 + tid * 16,
              (char*)&Wbuf[cur ^ 1][0] + r * 8192 + tid * 16);
      xa = *(const float4*)(xp + (kt + 1) * BK);
      xb = *(const float4*)(xp + (kt + 1) * BK + 4);
    }

    // compute on buf[cur]
#pragma unroll
    for (int ks = 0; ks < 2; ++ks) {
      bf16x8 af[4], bfr[2];
#pragma unroll
      for (int i = 0; i < 4; ++i)
        af[i] = *(const bf16x8*)((const char*)&Wbuf[cur][0] + a_off[ks][i]);
#pragma unroll
      for (int j = 0; j < 2; ++j)
        bfr[j] = *(const bf16x8*)((const char*)&Xbuf[cur][0] + b_off[ks][j]);
#pragma unroll
      for (int i = 0; i < 4; ++i)
#pragma unroll
        for (int j = 0; j < 2; ++j)
          acc[i][j] = __builtin_amdgcn_mfma_f32_16x16x32_bf16(af[i], bfr[j], acc[i][j], 0, 0, 0);
    }

    if (kt < KSTEPS - 1) {
      bf16x8 xv;
      xv[0] = (short)f2bfu(xa.x); xv[1] = (short)f2bfu(xa.y);
      xv[2] = (short)f2bfu(xa.z); xv[3] = (short)f2bfu(xa.w);
      xv[4] = (short)f2bfu(xb.x); xv[5] = (short)f2bfu(xb.y);
      xv[6] = (short)f2bfu(xb.z); xv[7] = (short)f2bfu(xb.w);
      *(bf16x8*)((char*)&Xbuf[cur ^ 1][0] + xw_off) = xv;
    }
    __syncthreads();
  }

  // D: n = wn*64 + i*16 + l16*4 + reg, m = m0 + wm*32 + j*16 + l15.
#pragma unroll
  for (int j = 0; j < 2; ++j) {
    const int m = m0 + wm * 32 + j * 16 + l15;
    if (m < N_NODES) {
#pragma unroll
      for (int i = 0; i < 4; ++i) {
        const int n = wn * 64 + i * 16 + l16 * 4;
        ushort4 o;
        o.x = f2bfu(acc[i][j][0]);
        o.y = f2bfu(acc[i][j][1]);
        o.z = f2bfu(acc[i][j][2]);
        o.w = f2bfu(acc[i][j][3]);
        *(ushort4*)&support[(size_t)m * D_OUT + n] = o;
      }
    }
  }
}

// ---------------------------------------------------------------------------
// Kernel 3: build capped per-dst edge lists (int atomics only).
// ---------------------------------------------------------------------------
__global__ __launch_bounds__(256) void build_kernel(const int* __restrict__ ei,
                                                    const float* __restrict__ ew,
                                                    int* __restrict__ deg,
                                                    int* __restrict__ csr_src,
                                                    float* __restrict__ csr_w) {
  const int e = blockIdx.x * 256 + threadIdx.x;
  if (e >= N_EDGES) return;
  const int src = ei[e];
  const int dst = ei[N_EDGES + e];
  const float w = ew[e];
  const int slot = atomicAdd(&deg[dst], 1);
  if (slot < CAP) {
    csr_src[dst * CAP + slot] = src;
    csr_w [dst * CAP + slot] = w;
  }
}

// ---------------------------------------------------------------------------
// Kernel 4: per-node gather-aggregate + epilogue. One wave per node.
// ---------------------------------------------------------------------------
__global__ __launch_bounds__(256) void agg_kernel(const u16* __restrict__ support,
                                                  const int* __restrict__ deg,
                                                  const int* __restrict__ csr_src,
                                                  const float* __restrict__ csr_w,
                                                  const float* __restrict__ norm,
                                                  const float* __restrict__ bias,
                                                  float* __restrict__ out) {
  const int lane = threadIdx.x & 63;
  const int wid  = threadIdx.x >> 6;
  const int node = blockIdx.x * 4 + wid;
  const int d    = min(deg[node], CAP);
  const int cb   = node * CAP;
  float a0 = 0.f, a1 = 0.f, a2 = 0.f, a3 = 0.f;
  for (int s = 0; s < d; ++s) {
    const int   src = csr_src[cb + s];
    const float wgt = csr_w [cb + s];
    const ushort4 v = *(const ushort4*)&support[(size_t)src * D_OUT + lane * 4];
    a0 = fmaf(wgt, bfu2f(v.x), a0);
    a1 = fmaf(wgt, bfu2f(v.y), a1);
    a2 = fmaf(wgt, bfu2f(v.z), a2);
    a3 = fmaf(wgt, bfu2f(v.w), a3);
  }
  const float rn = 1.0f / norm[node];
  const float4 b = *(const float4*)&bias[lane * 4];
  float o0 = fmaf(a0, rn, b.x);
  float o1 = fmaf(a1, rn, b.y);
  float o2 = fmaf(a2, rn, b.z);
  float o3 = fmaf(a3, rn, b.w);
  o0 = o0 > 0.f ? o0 : o0 * LEAKY;
  o1 = o1 > 0.f ? o1 : o1 * LEAKY;
  o2 = o2 > 0.f ? o2 : o2 * LEAKY;
  o3 = o3 > 0.f ? o3 : o3 * LEAKY;
  *(float4*)&out[(size_t)node * D_OUT + lane * 4] = make_float4(o0, o1, o2, o3);
}

// ---------------------------------------------------------------------------
// ws layout (bytes):
//   support  bf16  [50000][256]     @ 0          25,600,000
//   Wimg     bf16  16x[256][64] swz @ 25,600,000    524,288
//   csr_src  int   [50000][64]      @ 26,124,288 12,800,000
//   csr_w    float [50000][64]      @ 38,924,288 12,800,000
//   deg      int   [50000]          @ 51,724,288    200,000
// ---------------------------------------------------------------------------
extern "C" void kernel_launch(void* const* d_in, const int* in_sizes, int n_in,
                              void* d_out, int out_size, void* d_ws, size_t ws_size,
                              hipStream_t stream) {
  const float* x    = (const float*)d_in[0];
  const float* w    = (const float*)d_in[1];
  const float* bias = (const float*)d_in[2];
  const int*   ei   = (const int*)d_in[3];
  const float* ew   = (const float*)d_in[4];
  const float* norm = (const float*)d_in[5];
  float* out = (float*)d_out;

  char* ws = (char*)d_ws;
  u16*   support = (u16*)  (ws);
  char*  img     =         (ws + 25600000);
  int*   csr_src = (int*)  (ws + 26124288);
  float* csr_w   = (float*)(ws + 38924288);
  int*   deg     = (int*)  (ws + 51724288);

  hipMemsetAsync(deg, 0, N_NODES * sizeof(int), stream);
  wconv_kernel<<<128, 256, 0, stream>>>(w, img);
  gemm_kernel<<<(N_NODES + BM - 1) / BM, 512, 0, stream>>>(x, img, support);
  build_kernel<<<(N_EDGES + 255) / 256, 256, 0, stream>>>(ei, ew, deg, csr_src, csr_w);
  agg_kernel<<<N_NODES / 4, 256, 0, stream>>>(support, deg, csr_src, csr_w, norm, bias, out);
}

// Round 3
// 216.758 us; speedup vs baseline: 1.1937x; 1.0984x over previous
//
#include <hip/hip_runtime.h>
#include <hip/hip_bf16.h>

#define N_NODES 50000
#define N_EDGES 800000
#define D_IN    1024
#define D_OUT   256
#define CAP     64
#define LEAKY   0.01f

typedef __attribute__((ext_vector_type(8))) short bf16x8;
typedef __attribute__((ext_vector_type(4))) float f32x4;
typedef unsigned short u16;

__device__ __forceinline__ u16 f2bfu(float f) {
  uint32_t x = __float_as_uint(f);
  uint32_t r = (x + 0x7FFFu + ((x >> 16) & 1u)) >> 16;  // RNE
  return (u16)r;
}
__device__ __forceinline__ float bfu2f(u16 u) {
  return __uint_as_float(((uint32_t)u) << 16);
}
// XOR bank swizzle: flip byte bits 4-6 with row (byte>>7) low bits.
__device__ __forceinline__ int swz(int b) { return b ^ (((b >> 7) & 7) << 4); }

__device__ __forceinline__ void gll16(const void* g, void* l) {
  __builtin_amdgcn_global_load_lds(
      (const __attribute__((address_space(1))) uint32_t*)g,
      (__attribute__((address_space(3))) uint32_t*)l, 16, 0, 0);
}

// ---------------------------------------------------------------------------
// Kernel 1: weight fp32 [K=1024][N=256] -> bf16 swizzled "LDS image"
// (16 k-tiles x [256 n][64 k] x 32768 B). ALSO zeroes deg[] (2 ints/thread)
// -- replaces the pathological 116-us hipMemsetAsync fill. wconv precedes
// build on the stream, so deg is zero before any atomics.
// ---------------------------------------------------------------------------
__global__ __launch_bounds__(256) void wconv_kernel(const float* __restrict__ w,
                                                    char* __restrict__ img,
                                                    int* __restrict__ deg) {
  const int t   = blockIdx.x * 256 + threadIdx.x;   // 0..32767
  if (t < N_NODES) deg[t] = 0;
  const int t2 = t + 32768;
  if (t2 < N_NODES) deg[t2] = 0;

  const int n   = t & 255;
  const int kc  = (t >> 8) * 8;                     // k chunk of 8
  const int kt  = kc >> 6;
  const int kin = kc & 63;
  bf16x8 v;
#pragma unroll
  for (int i = 0; i < 8; ++i) v[i] = (short)f2bfu(w[(size_t)(kc + i) * D_OUT + n]);
  *(bf16x8*)(img + kt * 32768 + swz(n * 128 + kin * 2)) = v;
}

// ---------------------------------------------------------------------------
// Kernel 2: GEMM support = x @ W, bf16 MFMA.
// BM=64, BN=256(full), BK=64. 512 thr = 8 waves (2m x 4n), wave = 32m x 64n,
// acc[4][2]. Double-buffered LDS, one barrier per K-step; W via
// global_load_lds from the pre-swizzled image, X reg-staged + swizzled
// ds_write. Fragment reads bank-conflict-free.
// ---------------------------------------------------------------------------
#define BM 64
#define BK 64
#define KSTEPS (D_IN / BK)   // 16

__global__ __launch_bounds__(512) void gemm_kernel(const float* __restrict__ x,
                                                   const char* __restrict__ img,
                                                   u16* __restrict__ support) {
  __shared__ u16 Wbuf[2][16384];  // [256 n][64 k] swizzled, 32 KB each
  __shared__ u16 Xbuf[2][4096];   // [64 m][64 k] swizzled,  8 KB each

  const int tid  = threadIdx.x;
  const int lane = tid & 63;
  const int wid  = tid >> 6;
  const int wn   = wid & 3;    // n-group (64 cols)
  const int wm   = wid >> 2;   // m-group (32 rows)
  const int l15  = lane & 15;
  const int l16  = lane >> 4;
  const int m0   = blockIdx.x * BM;

  f32x4 acc[4][2];
#pragma unroll
  for (int i = 0; i < 4; ++i)
#pragma unroll
    for (int j = 0; j < 2; ++j) acc[i][j] = (f32x4)0.0f;

  const int xrow = tid >> 3;           // 0..63
  const int xk8  = (tid & 7) * 8;      // 0..56
  const int xrg  = min(m0 + xrow, N_NODES - 1);
  const float* xp = x + (size_t)xrg * D_IN + xk8;
  const int xw_off = swz(xrow * 128 + xk8 * 2);

  int a_off[2][4], b_off[2][2];
#pragma unroll
  for (int ks = 0; ks < 2; ++ks) {
#pragma unroll
    for (int i = 0; i < 4; ++i)
      a_off[ks][i] = swz((wn * 64 + i * 16 + l15) * 128 + ks * 64 + l16 * 16);
#pragma unroll
    for (int j = 0; j < 2; ++j)
      b_off[ks][j] = swz((wm * 32 + j * 16 + l15) * 128 + ks * 64 + l16 * 16);
  }

  // ---- prologue: stage k-tile 0 into buffer 0 ----
#pragma unroll
  for (int r = 0; r < 4; ++r)
    gll16(img + r * 8192 + tid * 16, (char*)&Wbuf[0][0] + r * 8192 + tid * 16);
  {
    const float4 xa = *(const float4*)(xp);
    const float4 xb = *(const float4*)(xp + 4);
    bf16x8 xv;
    xv[0] = (short)f2bfu(xa.x); xv[1] = (short)f2bfu(xa.y);
    xv[2] = (short)f2bfu(xa.z); xv[3] = (short)f2bfu(xa.w);
    xv[4] = (short)f2bfu(xb.x); xv[5] = (short)f2bfu(xb.y);
    xv[6] = (short)f2bfu(xb.z); xv[7] = (short)f2bfu(xb.w);
    *(bf16x8*)((char*)&Xbuf[0][0] + xw_off) = xv;
  }
  __syncthreads();

  for (int kt = 0; kt < KSTEPS; ++kt) {
    const int cur = kt & 1;
    float4 xa, xb;
    if (kt < KSTEPS - 1) {
#pragma unroll
      for (int r = 0; r < 4; ++r)
        gll16(img + (size_t)(kt + 1) * 32768 + r * 8192 + tid * 16,
              (char*)&Wbuf[cur ^ 1][0] + r * 8192 + tid * 16);
      xa = *(const float4*)(xp + (kt + 1) * BK);
      xb = *(const float4*)(xp + (kt + 1) * BK + 4);
    }

#pragma unroll
    for (int ks = 0; ks < 2; ++ks) {
      bf16x8 af[4], bfr[2];
#pragma unroll
      for (int i = 0; i < 4; ++i)
        af[i] = *(const bf16x8*)((const char*)&Wbuf[cur][0] + a_off[ks][i]);
#pragma unroll
      for (int j = 0; j < 2; ++j)
        bfr[j] = *(const bf16x8*)((const char*)&Xbuf[cur][0] + b_off[ks][j]);
#pragma unroll
      for (int i = 0; i < 4; ++i)
#pragma unroll
        for (int j = 0; j < 2; ++j)
          acc[i][j] = __builtin_amdgcn_mfma_f32_16x16x32_bf16(af[i], bfr[j], acc[i][j], 0, 0, 0);
    }

    if (kt < KSTEPS - 1) {
      bf16x8 xv;
      xv[0] = (short)f2bfu(xa.x); xv[1] = (short)f2bfu(xa.y);
      xv[2] = (short)f2bfu(xa.z); xv[3] = (short)f2bfu(xa.w);
      xv[4] = (short)f2bfu(xb.x); xv[5] = (short)f2bfu(xb.y);
      xv[6] = (short)f2bfu(xb.z); xv[7] = (short)f2bfu(xb.w);
      *(bf16x8*)((char*)&Xbuf[cur ^ 1][0] + xw_off) = xv;
    }
    __syncthreads();
  }

#pragma unroll
  for (int j = 0; j < 2; ++j) {
    const int m = m0 + wm * 32 + j * 16 + l15;
    if (m < N_NODES) {
#pragma unroll
      for (int i = 0; i < 4; ++i) {
        const int n = wn * 64 + i * 16 + l16 * 4;
        ushort4 o;
        o.x = f2bfu(acc[i][j][0]);
        o.y = f2bfu(acc[i][j][1]);
        o.z = f2bfu(acc[i][j][2]);
        o.w = f2bfu(acc[i][j][3]);
        *(ushort4*)&support[(size_t)m * D_OUT + n] = o;
      }
    }
  }
}

// ---------------------------------------------------------------------------
// Kernel 3: build capped per-dst edge lists (int atomics only). Entry is a
// fused int2 {src, weight_bits} -> one scattered 8B store per edge.
// ---------------------------------------------------------------------------
__global__ __launch_bounds__(256) void build_kernel(const int* __restrict__ ei,
                                                    const float* __restrict__ ew,
                                                    int* __restrict__ deg,
                                                    int2* __restrict__ csr) {
  const int e = blockIdx.x * 256 + threadIdx.x;
  if (e >= N_EDGES) return;
  const int src = ei[e];
  const int dst = ei[N_EDGES + e];
  const float w = ew[e];
  const int slot = atomicAdd(&deg[dst], 1);
  if (slot < CAP) {
    csr[dst * CAP + slot] = make_int2(src, __float_as_int(w));
  }
}

// ---------------------------------------------------------------------------
// Kernel 4: per-node gather-aggregate + epilogue. One wave per node; lane
// owns 4 channels (8B gather per lane, 512B/edge coalesced).
// ---------------------------------------------------------------------------
__global__ __launch_bounds__(256) void agg_kernel(const u16* __restrict__ support,
                                                  const int* __restrict__ deg,
                                                  const int2* __restrict__ csr,
                                                  const float* __restrict__ norm,
                                                  const float* __restrict__ bias,
                                                  float* __restrict__ out) {
  const int lane = threadIdx.x & 63;
  const int wid  = threadIdx.x >> 6;
  const int node = blockIdx.x * 4 + wid;   // grid 12500 -> exactly 50000
  const int d    = min(deg[node], CAP);
  const int cb   = node * CAP;
  float a0 = 0.f, a1 = 0.f, a2 = 0.f, a3 = 0.f;
  for (int s = 0; s < d; ++s) {
    const int2  e   = csr[cb + s];          // wave-uniform -> broadcast
    const float wgt = __int_as_float(e.y);
    const ushort4 v = *(const ushort4*)&support[(size_t)e.x * D_OUT + lane * 4];
    a0 = fmaf(wgt, bfu2f(v.x), a0);
    a1 = fmaf(wgt, bfu2f(v.y), a1);
    a2 = fmaf(wgt, bfu2f(v.z), a2);
    a3 = fmaf(wgt, bfu2f(v.w), a3);
  }
  const float rn = 1.0f / norm[node];
  const float4 b = *(const float4*)&bias[lane * 4];
  float o0 = fmaf(a0, rn, b.x);
  float o1 = fmaf(a1, rn, b.y);
  float o2 = fmaf(a2, rn, b.z);
  float o3 = fmaf(a3, rn, b.w);
  o0 = o0 > 0.f ? o0 : o0 * LEAKY;
  o1 = o1 > 0.f ? o1 : o1 * LEAKY;
  o2 = o2 > 0.f ? o2 : o2 * LEAKY;
  o3 = o3 > 0.f ? o3 : o3 * LEAKY;
  *(float4*)&out[(size_t)node * D_OUT + lane * 4] = make_float4(o0, o1, o2, o3);
}

// ---------------------------------------------------------------------------
// ws layout (bytes):
//   support  bf16  [50000][256]     @ 0          25,600,000
//   Wimg     bf16  16x[256][64] swz @ 25,600,000    524,288
//   csr      int2  [50000][64]      @ 26,124,288 25,600,000
//   deg      int   [50000]          @ 51,724,288    200,000
// ---------------------------------------------------------------------------
extern "C" void kernel_launch(void* const* d_in, const int* in_sizes, int n_in,
                              void* d_out, int out_size, void* d_ws, size_t ws_size,
                              hipStream_t stream) {
  const float* x    = (const float*)d_in[0];
  const float* w    = (const float*)d_in[1];
  const float* bias = (const float*)d_in[2];
  const int*   ei   = (const int*)d_in[3];
  const float* ew   = (const float*)d_in[4];
  const float* norm = (const float*)d_in[5];
  float* out = (float*)d_out;

  char* ws = (char*)d_ws;
  u16*   support = (u16*)  (ws);
  char*  img     =         (ws + 25600000);
  int2*  csr     = (int2*) (ws + 26124288);
  int*   deg     = (int*)  (ws + 51724288);

  wconv_kernel<<<128, 256, 0, stream>>>(w, img, deg);
  gemm_kernel<<<(N_NODES + BM - 1) / BM, 512, 0, stream>>>(x, img, support);
  build_kernel<<<(N_EDGES + 255) / 256, 256, 0, stream>>>(ei, ew, deg, csr);
  agg_kernel<<<N_NODES / 4, 256, 0, stream>>>(support, deg, csr, norm, bias, out);
}

// Round 5
// 175.293 us; speedup vs baseline: 1.4760x; 1.2365x over previous
//
#include <hip/hip_runtime.h>
#include <hip/hip_bf16.h>

#define N_NODES 50000
#define N_EDGES 800000
#define D_IN    1024
#define D_OUT   256
#define CAP     64
#define LEAKY   0.01f

typedef __attribute__((ext_vector_type(8))) short bf16x8;
typedef __attribute__((ext_vector_type(4))) float f32x4;
typedef unsigned short u16;

__device__ __forceinline__ u16 f2bfu(float f) {
  uint32_t x = __float_as_uint(f);
  uint32_t r = (x + 0x7FFFu + ((x >> 16) & 1u)) >> 16;  // RNE
  return (u16)r;
}
__device__ __forceinline__ float bfu2f(u16 u) {
  return __uint_as_float(((uint32_t)u) << 16);
}
// XOR bank swizzle: flip byte bits 4-6 with row (byte>>7) low bits.
__device__ __forceinline__ int swz(int b) { return b ^ (((b >> 7) & 7) << 4); }

__device__ __forceinline__ void gll16(const void* g, void* l) {
  __builtin_amdgcn_global_load_lds(
      (const __attribute__((address_space(1))) uint32_t*)g,
      (__attribute__((address_space(3))) uint32_t*)l, 16, 0, 0);
}

// ---------------------------------------------------------------------------
// Kernel 1: weight fp32 [K=1024][N=256] -> bf16 swizzled "LDS image"
// (16 k-tiles x [256 n][64 k] x 32768 B). Also zeroes deg[].
// ---------------------------------------------------------------------------
__global__ __launch_bounds__(256) void wconv_kernel(const float* __restrict__ w,
                                                    char* __restrict__ img,
                                                    int* __restrict__ deg) {
  const int t   = blockIdx.x * 256 + threadIdx.x;   // 0..32767
  if (t < N_NODES) deg[t] = 0;
  const int t2 = t + 32768;
  if (t2 < N_NODES) deg[t2] = 0;

  const int n   = t & 255;
  const int kc  = (t >> 8) * 8;
  const int kt  = kc >> 6;
  const int kin = kc & 63;
  bf16x8 v;
#pragma unroll
  for (int i = 0; i < 8; ++i) v[i] = (short)f2bfu(w[(size_t)(kc + i) * D_OUT + n]);
  *(bf16x8*)(img + kt * 32768 + swz(n * 128 + kin * 2)) = v;
}

// ---------------------------------------------------------------------------
// Kernel 2: GEMM support = x @ W, bf16 MFMA. BM=64, BN=256, BK=64.
// 8 waves, double-buffered LDS, W via global_load_lds from swizzled image.
// ---------------------------------------------------------------------------
#define BM 64
#define BK 64
#define KSTEPS (D_IN / BK)   // 16

__global__ __launch_bounds__(512) void gemm_kernel(const float* __restrict__ x,
                                                   const char* __restrict__ img,
                                                   u16* __restrict__ support) {
  __shared__ u16 Wbuf[2][16384];  // [256 n][64 k] swizzled, 32 KB each
  __shared__ u16 Xbuf[2][4096];   // [64 m][64 k] swizzled,  8 KB each

  const int tid  = threadIdx.x;
  const int lane = tid & 63;
  const int wid  = tid >> 6;
  const int wn   = wid & 3;
  const int wm   = wid >> 2;
  const int l15  = lane & 15;
  const int l16  = lane >> 4;
  const int m0   = blockIdx.x * BM;

  f32x4 acc[4][2];
#pragma unroll
  for (int i = 0; i < 4; ++i)
#pragma unroll
    for (int j = 0; j < 2; ++j) acc[i][j] = (f32x4)0.0f;

  const int xrow = tid >> 3;
  const int xk8  = (tid & 7) * 8;
  const int xrg  = min(m0 + xrow, N_NODES - 1);
  const float* xp = x + (size_t)xrg * D_IN + xk8;
  const int xw_off = swz(xrow * 128 + xk8 * 2);

  int a_off[2][4], b_off[2][2];
#pragma unroll
  for (int ks = 0; ks < 2; ++ks) {
#pragma unroll
    for (int i = 0; i < 4; ++i)
      a_off[ks][i] = swz((wn * 64 + i * 16 + l15) * 128 + ks * 64 + l16 * 16);
#pragma unroll
    for (int j = 0; j < 2; ++j)
      b_off[ks][j] = swz((wm * 32 + j * 16 + l15) * 128 + ks * 64 + l16 * 16);
  }

#pragma unroll
  for (int r = 0; r < 4; ++r)
    gll16(img + r * 8192 + tid * 16, (char*)&Wbuf[0][0] + r * 8192 + tid * 16);
  {
    const float4 xa = *(const float4*)(xp);
    const float4 xb = *(const float4*)(xp + 4);
    bf16x8 xv;
    xv[0] = (short)f2bfu(xa.x); xv[1] = (short)f2bfu(xa.y);
    xv[2] = (short)f2bfu(xa.z); xv[3] = (short)f2bfu(xa.w);
    xv[4] = (short)f2bfu(xb.x); xv[5] = (short)f2bfu(xb.y);
    xv[6] = (short)f2bfu(xb.z); xv[7] = (short)f2bfu(xb.w);
    *(bf16x8*)((char*)&Xbuf[0][0] + xw_off) = xv;
  }
  __syncthreads();

  for (int kt = 0; kt < KSTEPS; ++kt) {
    const int cur = kt & 1;
    float4 xa, xb;
    if (kt < KSTEPS - 1) {
#pragma unroll
      for (int r = 0; r < 4; ++r)
        gll16(img + (size_t)(kt + 1) * 32768 + r * 8192 + tid * 16,
              (char*)&Wbuf[cur ^ 1][0] + r * 8192 + tid * 16);
      xa = *(const float4*)(xp + (kt + 1) * BK);
      xb = *(const float4*)(xp + (kt + 1) * BK + 4);
    }

#pragma unroll
    for (int ks = 0; ks < 2; ++ks) {
      bf16x8 af[4], bfr[2];
#pragma unroll
      for (int i = 0; i < 4; ++i)
        af[i] = *(const bf16x8*)((const char*)&Wbuf[cur][0] + a_off[ks][i]);
#pragma unroll
      for (int j = 0; j < 2; ++j)
        bfr[j] = *(const bf16x8*)((const char*)&Xbuf[cur][0] + b_off[ks][j]);
#pragma unroll
      for (int i = 0; i < 4; ++i)
#pragma unroll
        for (int j = 0; j < 2; ++j)
          acc[i][j] = __builtin_amdgcn_mfma_f32_16x16x32_bf16(af[i], bfr[j], acc[i][j], 0, 0, 0);
    }

    if (kt < KSTEPS - 1) {
      bf16x8 xv;
      xv[0] = (short)f2bfu(xa.x); xv[1] = (short)f2bfu(xa.y);
      xv[2] = (short)f2bfu(xa.z); xv[3] = (short)f2bfu(xa.w);
      xv[4] = (short)f2bfu(xb.x); xv[5] = (short)f2bfu(xb.y);
      xv[6] = (short)f2bfu(xb.z); xv[7] = (short)f2bfu(xb.w);
      *(bf16x8*)((char*)&Xbuf[cur ^ 1][0] + xw_off) = xv;
    }
    __syncthreads();
  }

#pragma unroll
  for (int j = 0; j < 2; ++j) {
    const int m = m0 + wm * 32 + j * 16 + l15;
    if (m < N_NODES) {
#pragma unroll
      for (int i = 0; i < 4; ++i) {
        const int n = wn * 64 + i * 16 + l16 * 4;
        ushort4 o;
        o.x = f2bfu(acc[i][j][0]);
        o.y = f2bfu(acc[i][j][1]);
        o.z = f2bfu(acc[i][j][2]);
        o.w = f2bfu(acc[i][j][3]);
        *(ushort4*)&support[(size_t)m * D_OUT + n] = o;
      }
    }
  }
}

// ---------------------------------------------------------------------------
// Kernel 3: build capped per-dst edge lists (int atomics only).
// ---------------------------------------------------------------------------
__global__ __launch_bounds__(256) void build_kernel(const int* __restrict__ ei,
                                                    const float* __restrict__ ew,
                                                    int* __restrict__ deg,
                                                    int2* __restrict__ csr) {
  const int e = blockIdx.x * 256 + threadIdx.x;
  if (e >= N_EDGES) return;
  const int src = ei[e];
  const int dst = ei[N_EDGES + e];
  const float w = ew[e];
  const int slot = atomicAdd(&deg[dst], 1);
  if (slot < CAP) {
    csr[dst * CAP + slot] = make_int2(src, __float_as_int(w));
  }
}

// ---------------------------------------------------------------------------
// Kernel 4: per-node gather-aggregate + epilogue. One wave per node.
// 8x unrolled edge loop: burst-load 8 csr entries (4x int4), issue all 8
// support gathers back-to-back, then FMA -- turns ~16 exposed memory
// round-trips per node into ~2 (latency-bound -> ILP fix, Guideline 7).
// Non-temporal out store (ext-vector f32x4, not HIP float4) keeps the 51 MB
// out stream from evicting support.
// ---------------------------------------------------------------------------
__global__ __launch_bounds__(256) void agg_kernel(const u16* __restrict__ support,
                                                  const int* __restrict__ deg,
                                                  const int2* __restrict__ csr,
                                                  const float* __restrict__ norm,
                                                  const float* __restrict__ bias,
                                                  float* __restrict__ out) {
  const int lane = threadIdx.x & 63;
  const int wid  = threadIdx.x >> 6;
  const int node = blockIdx.x * 4 + wid;   // grid 12500 -> exactly 50000
  const int d    = min(deg[node], CAP);
  const int cb   = node * CAP;
  const int ch   = lane * 4;

  float a0 = 0.f, a1 = 0.f, a2 = 0.f, a3 = 0.f;
  int s = 0;
  for (; s + 8 <= d; s += 8) {
    const int4 q0 = *(const int4*)&csr[cb + s];
    const int4 q1 = *(const int4*)&csr[cb + s + 2];
    const int4 q2 = *(const int4*)&csr[cb + s + 4];
    const int4 q3 = *(const int4*)&csr[cb + s + 6];
    const ushort4 v0 = *(const ushort4*)&support[(size_t)q0.x * D_OUT + ch];
    const ushort4 v1 = *(const ushort4*)&support[(size_t)q0.z * D_OUT + ch];
    const ushort4 v2 = *(const ushort4*)&support[(size_t)q1.x * D_OUT + ch];
    const ushort4 v3 = *(const ushort4*)&support[(size_t)q1.z * D_OUT + ch];
    const ushort4 v4 = *(const ushort4*)&support[(size_t)q2.x * D_OUT + ch];
    const ushort4 v5 = *(const ushort4*)&support[(size_t)q2.z * D_OUT + ch];
    const ushort4 v6 = *(const ushort4*)&support[(size_t)q3.x * D_OUT + ch];
    const ushort4 v7 = *(const ushort4*)&support[(size_t)q3.z * D_OUT + ch];
    const float w0 = __int_as_float(q0.y), w1 = __int_as_float(q0.w);
    const float w2 = __int_as_float(q1.y), w3 = __int_as_float(q1.w);
    const float w4 = __int_as_float(q2.y), w5 = __int_as_float(q2.w);
    const float w6 = __int_as_float(q3.y), w7 = __int_as_float(q3.w);
    a0 = fmaf(w0, bfu2f(v0.x), a0); a1 = fmaf(w0, bfu2f(v0.y), a1);
    a2 = fmaf(w0, bfu2f(v0.z), a2); a3 = fmaf(w0, bfu2f(v0.w), a3);
    a0 = fmaf(w1, bfu2f(v1.x), a0); a1 = fmaf(w1, bfu2f(v1.y), a1);
    a2 = fmaf(w1, bfu2f(v1.z), a2); a3 = fmaf(w1, bfu2f(v1.w), a3);
    a0 = fmaf(w2, bfu2f(v2.x), a0); a1 = fmaf(w2, bfu2f(v2.y), a1);
    a2 = fmaf(w2, bfu2f(v2.z), a2); a3 = fmaf(w2, bfu2f(v2.w), a3);
    a0 = fmaf(w3, bfu2f(v3.x), a0); a1 = fmaf(w3, bfu2f(v3.y), a1);
    a2 = fmaf(w3, bfu2f(v3.z), a2); a3 = fmaf(w3, bfu2f(v3.w), a3);
    a0 = fmaf(w4, bfu2f(v4.x), a0); a1 = fmaf(w4, bfu2f(v4.y), a1);
    a2 = fmaf(w4, bfu2f(v4.z), a2); a3 = fmaf(w4, bfu2f(v4.w), a3);
    a0 = fmaf(w5, bfu2f(v5.x), a0); a1 = fmaf(w5, bfu2f(v5.y), a1);
    a2 = fmaf(w5, bfu2f(v5.z), a2); a3 = fmaf(w5, bfu2f(v5.w), a3);
    a0 = fmaf(w6, bfu2f(v6.x), a0); a1 = fmaf(w6, bfu2f(v6.y), a1);
    a2 = fmaf(w6, bfu2f(v6.z), a2); a3 = fmaf(w6, bfu2f(v6.w), a3);
    a0 = fmaf(w7, bfu2f(v7.x), a0); a1 = fmaf(w7, bfu2f(v7.y), a1);
    a2 = fmaf(w7, bfu2f(v7.z), a2); a3 = fmaf(w7, bfu2f(v7.w), a3);
  }
  for (; s < d; ++s) {
    const int2  e   = csr[cb + s];
    const float wgt = __int_as_float(e.y);
    const ushort4 v = *(const ushort4*)&support[(size_t)e.x * D_OUT + ch];
    a0 = fmaf(wgt, bfu2f(v.x), a0);
    a1 = fmaf(wgt, bfu2f(v.y), a1);
    a2 = fmaf(wgt, bfu2f(v.z), a2);
    a3 = fmaf(wgt, bfu2f(v.w), a3);
  }

  const float rn = 1.0f / norm[node];
  const float4 b = *(const float4*)&bias[ch];
  float o0 = fmaf(a0, rn, b.x);
  float o1 = fmaf(a1, rn, b.y);
  float o2 = fmaf(a2, rn, b.z);
  float o3 = fmaf(a3, rn, b.w);
  o0 = o0 > 0.f ? o0 : o0 * LEAKY;
  o1 = o1 > 0.f ? o1 : o1 * LEAKY;
  o2 = o2 > 0.f ? o2 : o2 * LEAKY;
  o3 = o3 > 0.f ? o3 : o3 * LEAKY;
  f32x4 ov;
  ov[0] = o0; ov[1] = o1; ov[2] = o2; ov[3] = o3;
  __builtin_nontemporal_store(ov, (f32x4*)&out[(size_t)node * D_OUT + ch]);
}

// ---------------------------------------------------------------------------
// ws layout (bytes):
//   support  bf16  [50000][256]     @ 0          25,600,000
//   Wimg     bf16  16x[256][64] swz @ 25,600,000    524,288
//   csr      int2  [50000][64]      @ 26,124,288 25,600,000
//   deg      int   [50000]          @ 51,724,288    200,000
// ---------------------------------------------------------------------------
extern "C" void kernel_launch(void* const* d_in, const int* in_sizes, int n_in,
                              void* d_out, int out_size, void* d_ws, size_t ws_size,
                              hipStream_t stream) {
  const float* x    = (const float*)d_in[0];
  const float* w    = (const float*)d_in[1];
  const float* bias = (const float*)d_in[2];
  const int*   ei   = (const int*)d_in[3];
  const float* ew   = (const float*)d_in[4];
  const float* norm = (const float*)d_in[5];
  float* out = (float*)d_out;

  char* ws = (char*)d_ws;
  u16*   support = (u16*)  (ws);
  char*  img     =         (ws + 25600000);
  int2*  csr     = (int2*) (ws + 26124288);
  int*   deg     = (int*)  (ws + 51724288);

  wconv_kernel<<<128, 256, 0, stream>>>(w, img, deg);
  gemm_kernel<<<(N_NODES + BM - 1) / BM, 512, 0, stream>>>(x, img, support);
  build_kernel<<<(N_EDGES + 255) / 256, 256, 0, stream>>>(ei, ew, deg, csr);
  agg_kernel<<<N_NODES / 4, 256, 0, stream>>>(support, deg, csr, norm, bias, out);
}

// Round 6
// 150.069 us; speedup vs baseline: 1.7241x; 1.1681x over previous
//
#include <hip/hip_runtime.h>
#include <hip/hip_bf16.h>

#define N_NODES 50000
#define N_EDGES 800000
#define D_IN    1024
#define D_OUT   256
#define CAP     64
#define LEAKY   0.01f

typedef __attribute__((ext_vector_type(8))) short bf16x8;
typedef __attribute__((ext_vector_type(4))) float f32x4;
typedef __attribute__((ext_vector_type(4))) int   i32x4;
typedef unsigned short u16;

__device__ __forceinline__ u16 f2bfu(float f) {
  uint32_t x = __float_as_uint(f);
  uint32_t r = (x + 0x7FFFu + ((x >> 16) & 1u)) >> 16;  // RNE
  return (u16)r;
}
__device__ __forceinline__ float bfu2f(u16 u) {
  return __uint_as_float(((uint32_t)u) << 16);
}
// XOR bank swizzle: flip byte bits 4-6 with row (byte>>7) low bits.
__device__ __forceinline__ int swz(int b) { return b ^ (((b >> 7) & 7) << 4); }

__device__ __forceinline__ void gll16(const void* g, void* l) {
  __builtin_amdgcn_global_load_lds(
      (const __attribute__((address_space(1))) uint32_t*)g,
      (__attribute__((address_space(3))) uint32_t*)l, 16, 0, 0);
}

// ---------------------------------------------------------------------------
// Kernel 1: weight fp32 [K=1024][N=256] -> bf16 swizzled "LDS image"
// (16 k-tiles x [256 n][64 k] x 32768 B). Also zeroes deg[].
// ---------------------------------------------------------------------------
__global__ __launch_bounds__(256) void wconv_kernel(const float* __restrict__ w,
                                                    char* __restrict__ img,
                                                    int* __restrict__ deg) {
  const int t   = blockIdx.x * 256 + threadIdx.x;   // 0..32767
  if (t < N_NODES) deg[t] = 0;
  const int t2 = t + 32768;
  if (t2 < N_NODES) deg[t2] = 0;

  const int n   = t & 255;
  const int kc  = (t >> 8) * 8;
  const int kt  = kc >> 6;
  const int kin = kc & 63;
  bf16x8 v;
#pragma unroll
  for (int i = 0; i < 8; ++i) v[i] = (short)f2bfu(w[(size_t)(kc + i) * D_OUT + n]);
  *(bf16x8*)(img + kt * 32768 + swz(n * 128 + kin * 2)) = v;
}

// ---------------------------------------------------------------------------
// Kernel 2 (FUSED): build-blocks + GEMM-blocks in one dispatch.
//   blocks [0, BUILD_BLOCKS)              : grid-stride edge-list build
//   blocks [BUILD_BLOCKS, +782)           : GEMM support = x @ W (bf16 MFMA)
// Build uses atomics + scattered 8B stores (resources the GEMM barely
// touches) and dispatches FIRST, so it overlaps the GEMM instead of
// serializing ~20 us after it. deg[] was zeroed by wconv (prior kernel).
// GEMM: BM=64, BN=256, BK=64, 8 waves, double-buffered LDS, W via
// global_load_lds from the pre-swizzled image, X reg-staged + swizzled.
// ---------------------------------------------------------------------------
#define BM 64
#define BK 64
#define KSTEPS (D_IN / BK)   // 16
#define GEMM_BLOCKS ((N_NODES + BM - 1) / BM)   // 782
#define BUILD_BLOCKS 64

__global__ __launch_bounds__(512) void gemm_build_kernel(
    const float* __restrict__ x, const char* __restrict__ img,
    u16* __restrict__ support,
    const int* __restrict__ ei, const float* __restrict__ ew,
    int* __restrict__ deg, int2* __restrict__ csr) {
  __shared__ u16 Wbuf[2][16384];  // [256 n][64 k] swizzled, 32 KB each
  __shared__ u16 Xbuf[2][4096];   // [64 m][64 k] swizzled,  8 KB each

  if (blockIdx.x < BUILD_BLOCKS) {
    // ---------------- build path ----------------
    const int t0 = blockIdx.x * 512 + threadIdx.x;      // 0..32767
    for (int e = t0; e < N_EDGES; e += BUILD_BLOCKS * 512) {
      const int src = ei[e];
      const int dst = ei[N_EDGES + e];
      const float w = ew[e];
      const int slot = atomicAdd(&deg[dst], 1);
      if (slot < CAP) {
        csr[dst * CAP + slot] = make_int2(src, __float_as_int(w));
      }
    }
    return;
  }

  // ---------------- GEMM path ----------------
  const int tid  = threadIdx.x;
  const int lane = tid & 63;
  const int wid  = tid >> 6;
  const int wn   = wid & 3;
  const int wm   = wid >> 2;
  const int l15  = lane & 15;
  const int l16  = lane >> 4;
  const int m0   = (blockIdx.x - BUILD_BLOCKS) * BM;

  f32x4 acc[4][2];
#pragma unroll
  for (int i = 0; i < 4; ++i)
#pragma unroll
    for (int j = 0; j < 2; ++j) acc[i][j] = (f32x4)0.0f;

  const int xrow = tid >> 3;
  const int xk8  = (tid & 7) * 8;
  const int xrg  = min(m0 + xrow, N_NODES - 1);
  const float* xp = x + (size_t)xrg * D_IN + xk8;
  const int xw_off = swz(xrow * 128 + xk8 * 2);

  int a_off[2][4], b_off[2][2];
#pragma unroll
  for (int ks = 0; ks < 2; ++ks) {
#pragma unroll
    for (int i = 0; i < 4; ++i)
      a_off[ks][i] = swz((wn * 64 + i * 16 + l15) * 128 + ks * 64 + l16 * 16);
#pragma unroll
    for (int j = 0; j < 2; ++j)
      b_off[ks][j] = swz((wm * 32 + j * 16 + l15) * 128 + ks * 64 + l16 * 16);
  }

#pragma unroll
  for (int r = 0; r < 4; ++r)
    gll16(img + r * 8192 + tid * 16, (char*)&Wbuf[0][0] + r * 8192 + tid * 16);
  {
    const float4 xa = *(const float4*)(xp);
    const float4 xb = *(const float4*)(xp + 4);
    bf16x8 xv;
    xv[0] = (short)f2bfu(xa.x); xv[1] = (short)f2bfu(xa.y);
    xv[2] = (short)f2bfu(xa.z); xv[3] = (short)f2bfu(xa.w);
    xv[4] = (short)f2bfu(xb.x); xv[5] = (short)f2bfu(xb.y);
    xv[6] = (short)f2bfu(xb.z); xv[7] = (short)f2bfu(xb.w);
    *(bf16x8*)((char*)&Xbuf[0][0] + xw_off) = xv;
  }
  __syncthreads();

  for (int kt = 0; kt < KSTEPS; ++kt) {
    const int cur = kt & 1;
    float4 xa, xb;
    if (kt < KSTEPS - 1) {
#pragma unroll
      for (int r = 0; r < 4; ++r)
        gll16(img + (size_t)(kt + 1) * 32768 + r * 8192 + tid * 16,
              (char*)&Wbuf[cur ^ 1][0] + r * 8192 + tid * 16);
      xa = *(const float4*)(xp + (kt + 1) * BK);
      xb = *(const float4*)(xp + (kt + 1) * BK + 4);
    }

#pragma unroll
    for (int ks = 0; ks < 2; ++ks) {
      bf16x8 af[4], bfr[2];
#pragma unroll
      for (int i = 0; i < 4; ++i)
        af[i] = *(const bf16x8*)((const char*)&Wbuf[cur][0] + a_off[ks][i]);
#pragma unroll
      for (int j = 0; j < 2; ++j)
        bfr[j] = *(const bf16x8*)((const char*)&Xbuf[cur][0] + b_off[ks][j]);
#pragma unroll
      for (int i = 0; i < 4; ++i)
#pragma unroll
        for (int j = 0; j < 2; ++j)
          acc[i][j] = __builtin_amdgcn_mfma_f32_16x16x32_bf16(af[i], bfr[j], acc[i][j], 0, 0, 0);
    }

    if (kt < KSTEPS - 1) {
      bf16x8 xv;
      xv[0] = (short)f2bfu(xa.x); xv[1] = (short)f2bfu(xa.y);
      xv[2] = (short)f2bfu(xa.z); xv[3] = (short)f2bfu(xa.w);
      xv[4] = (short)f2bfu(xb.x); xv[5] = (short)f2bfu(xb.y);
      xv[6] = (short)f2bfu(xb.z); xv[7] = (short)f2bfu(xb.w);
      *(bf16x8*)((char*)&Xbuf[cur ^ 1][0] + xw_off) = xv;
    }
    __syncthreads();
  }

#pragma unroll
  for (int j = 0; j < 2; ++j) {
    const int m = m0 + wm * 32 + j * 16 + l15;
    if (m < N_NODES) {
#pragma unroll
      for (int i = 0; i < 4; ++i) {
        const int n = wn * 64 + i * 16 + l16 * 4;
        ushort4 o;
        o.x = f2bfu(acc[i][j][0]);
        o.y = f2bfu(acc[i][j][1]);
        o.z = f2bfu(acc[i][j][2]);
        o.w = f2bfu(acc[i][j][3]);
        *(ushort4*)&support[(size_t)m * D_OUT + n] = o;
      }
    }
  }
}

// ---------------------------------------------------------------------------
// Kernel 3: per-node gather-aggregate + epilogue. One wave per node.
// 16-deep gather pipeline (16 support rows in flight), then an 8-batch and
// a scalar tail. csr loads are non-temporal (read-once; keep L2 for
// support). Non-temporal out store keeps the 51 MB stream out of L2.
// ---------------------------------------------------------------------------
__global__ __launch_bounds__(256) void agg_kernel(const u16* __restrict__ support,
                                                  const int* __restrict__ deg,
                                                  const int2* __restrict__ csr,
                                                  const float* __restrict__ norm,
                                                  const float* __restrict__ bias,
                                                  float* __restrict__ out) {
  const int lane = threadIdx.x & 63;
  const int wid  = threadIdx.x >> 6;
  const int node = blockIdx.x * 4 + wid;   // grid 12500 -> exactly 50000
  const int d    = min(deg[node], CAP);
  const int cb   = node * CAP;
  const int ch   = lane * 4;

  float a0 = 0.f, a1 = 0.f, a2 = 0.f, a3 = 0.f;
  int s = 0;

  for (; s + 16 <= d; s += 16) {
    i32x4 q[8];
#pragma unroll
    for (int i = 0; i < 8; ++i)
      q[i] = __builtin_nontemporal_load((const i32x4*)&csr[cb + s + 2 * i]);
    ushort4 v[16];
#pragma unroll
    for (int i = 0; i < 8; ++i) {
      v[2 * i]     = *(const ushort4*)&support[(size_t)q[i][0] * D_OUT + ch];
      v[2 * i + 1] = *(const ushort4*)&support[(size_t)q[i][2] * D_OUT + ch];
    }
#pragma unroll
    for (int i = 0; i < 8; ++i) {
      const float wa = __int_as_float(q[i][1]);
      const float wb = __int_as_float(q[i][3]);
      a0 = fmaf(wa, bfu2f(v[2 * i].x), a0);
      a1 = fmaf(wa, bfu2f(v[2 * i].y), a1);
      a2 = fmaf(wa, bfu2f(v[2 * i].z), a2);
      a3 = fmaf(wa, bfu2f(v[2 * i].w), a3);
      a0 = fmaf(wb, bfu2f(v[2 * i + 1].x), a0);
      a1 = fmaf(wb, bfu2f(v[2 * i + 1].y), a1);
      a2 = fmaf(wb, bfu2f(v[2 * i + 1].z), a2);
      a3 = fmaf(wb, bfu2f(v[2 * i + 1].w), a3);
    }
  }

  for (; s + 8 <= d; s += 8) {
    i32x4 q[4];
#pragma unroll
    for (int i = 0; i < 4; ++i)
      q[i] = __builtin_nontemporal_load((const i32x4*)&csr[cb + s + 2 * i]);
    ushort4 v[8];
#pragma unroll
    for (int i = 0; i < 4; ++i) {
      v[2 * i]     = *(const ushort4*)&support[(size_t)q[i][0] * D_OUT + ch];
      v[2 * i + 1] = *(const ushort4*)&support[(size_t)q[i][2] * D_OUT + ch];
    }
#pragma unroll
    for (int i = 0; i < 4; ++i) {
      const float wa = __int_as_float(q[i][1]);
      const float wb = __int_as_float(q[i][3]);
      a0 = fmaf(wa, bfu2f(v[2 * i].x), a0);
      a1 = fmaf(wa, bfu2f(v[2 * i].y), a1);
      a2 = fmaf(wa, bfu2f(v[2 * i].z), a2);
      a3 = fmaf(wa, bfu2f(v[2 * i].w), a3);
      a0 = fmaf(wb, bfu2f(v[2 * i + 1].x), a0);
      a1 = fmaf(wb, bfu2f(v[2 * i + 1].y), a1);
      a2 = fmaf(wb, bfu2f(v[2 * i + 1].z), a2);
      a3 = fmaf(wb, bfu2f(v[2 * i + 1].w), a3);
    }
  }

  for (; s < d; ++s) {
    const int2  e   = csr[cb + s];
    const float wgt = __int_as_float(e.y);
    const ushort4 v = *(const ushort4*)&support[(size_t)e.x * D_OUT + ch];
    a0 = fmaf(wgt, bfu2f(v.x), a0);
    a1 = fmaf(wgt, bfu2f(v.y), a1);
    a2 = fmaf(wgt, bfu2f(v.z), a2);
    a3 = fmaf(wgt, bfu2f(v.w), a3);
  }

  const float rn = 1.0f / norm[node];
  const float4 b = *(const float4*)&bias[ch];
  float o0 = fmaf(a0, rn, b.x);
  float o1 = fmaf(a1, rn, b.y);
  float o2 = fmaf(a2, rn, b.z);
  float o3 = fmaf(a3, rn, b.w);
  o0 = o0 > 0.f ? o0 : o0 * LEAKY;
  o1 = o1 > 0.f ? o1 : o1 * LEAKY;
  o2 = o2 > 0.f ? o2 : o2 * LEAKY;
  o3 = o3 > 0.f ? o3 : o3 * LEAKY;
  f32x4 ov;
  ov[0] = o0; ov[1] = o1; ov[2] = o2; ov[3] = o3;
  __builtin_nontemporal_store(ov, (f32x4*)&out[(size_t)node * D_OUT + ch]);
}

// ---------------------------------------------------------------------------
// ws layout (bytes):
//   support  bf16  [50000][256]     @ 0          25,600,000
//   Wimg     bf16  16x[256][64] swz @ 25,600,000    524,288
//   csr      int2  [50000][64]      @ 26,124,288 25,600,000
//   deg      int   [50000]          @ 51,724,288    200,000
// ---------------------------------------------------------------------------
extern "C" void kernel_launch(void* const* d_in, const int* in_sizes, int n_in,
                              void* d_out, int out_size, void* d_ws, size_t ws_size,
                              hipStream_t stream) {
  const float* x    = (const float*)d_in[0];
  const float* w    = (const float*)d_in[1];
  const float* bias = (const float*)d_in[2];
  const int*   ei   = (const int*)d_in[3];
  const float* ew   = (const float*)d_in[4];
  const float* norm = (const float*)d_in[5];
  float* out = (float*)d_out;

  char* ws = (char*)d_ws;
  u16*   support = (u16*)  (ws);
  char*  img     =         (ws + 25600000);
  int2*  csr     = (int2*) (ws + 26124288);
  int*   deg     = (int*)  (ws + 51724288);

  wconv_kernel<<<128, 256, 0, stream>>>(w, img, deg);
  gemm_build_kernel<<<BUILD_BLOCKS + GEMM_BLOCKS, 512, 0, stream>>>(
      x, img, support, ei, ew, deg, csr);
  agg_kernel<<<N_NODES / 4, 256, 0, stream>>>(support, deg, csr, norm, bias, out);
}